// Round 2
// baseline (815.240 us; speedup 1.0000x reference)
//
#include <hip/hip_runtime.h>
#include <stdint.h>

// HashGrid3D: L=16 levels, T=2^19 entries/level, F=2 features, trilinear interp.
// One thread per point. Restructured for memory-level parallelism:
//  - 4 levels per batch = 32 independent float2 gathers issued back-to-back
//  - depth-2 software pipeline: batch b+1's loads are in flight while batch b
//    is consumed (compiler inserts precise vmcnt waits since gA/gB alternate)
//  - __launch_bounds__(256,2) frees the register allocator (~64 payload VGPRs
//    per batch x 2 batches live) instead of the 36-VGPR / 8-loads-in-flight
//    schedule the default heuristic produced.
//  - per-batch nontemporal stores keep the 128 MB output stream from evicting
//    hot table lines out of the 4 MB per-XCD L2.

constexpr int   LVL   = 16;
constexpr int   TBL   = 524288;          // 2^19
constexpr uint32_t TMASK = 0x7FFFFu;     // T-1
constexpr uint32_t P2 = 2654435761u;
constexpr uint32_t P3 = 805459861u;
// RES[l] = round(16 * (512/16)^(l/15))
constexpr int RESV[LVL] = {16, 20, 25, 32, 40, 51, 64, 81,
                           102, 128, 161, 203, 256, 323, 406, 512};

constexpr int NB = 4;                    // levels per batch

typedef float f32x4 __attribute__((ext_vector_type(4)));  // builtin-compatible

struct Frac { float tx, ty, tz; };

template<int L0>
__device__ __forceinline__ void issue_batch(const float2* __restrict__ tables,
                                            float x, float y, float z,
                                            float2 (&g)[NB * 8], Frac (&fr)[NB])
{
    #pragma unroll
    for (int j = 0; j < NB; ++j) {
        const int l = L0 + j;            // compile-time after unroll
        const int N = RESV[l];
        const float2* __restrict__ tbl = tables + (size_t)l * TBL;

        float sx = x * (float)N, sy = y * (float)N, sz = z * (float)N;
        float fx = floorf(sx), fy = floorf(sy), fz = floorf(sz);
        fr[j].tx = sx - fx; fr[j].ty = sy - fy; fr[j].tz = sz - fz;
        int ix = (int)fx, iy = (int)fy, iz = (int)fz;

        // reference applies (i0 + off) % N to every corner; i0 can hit N on
        // the fp rounding edge, so wrap corner 0 too.
        int ix0 = (ix >= N) ? ix - N : ix;
        int iy0 = (iy >= N) ? iy - N : iy;
        int iz0 = (iz >= N) ? iz - N : iz;
        int ix1 = ix + 1; ix1 = (ix1 >= N) ? ix1 - N : ix1;
        int iy1 = iy + 1; iy1 = (iy1 >= N) ? iy1 - N : iy1;
        int iz1 = iz + 1; iz1 = (iz1 >= N) ? iz1 - N : iz1;

        uint32_t hx0 = (uint32_t)ix0;           // prime 1
        uint32_t hx1 = (uint32_t)ix1;
        uint32_t hy0 = (uint32_t)iy0 * P2;
        uint32_t hy1 = (uint32_t)iy1 * P2;
        uint32_t hz0 = (uint32_t)iz0 * P3;
        uint32_t hz1 = (uint32_t)iz1 * P3;

        g[j*8+0] = tbl[(hx0 ^ hy0 ^ hz0) & TMASK];
        g[j*8+1] = tbl[(hx1 ^ hy0 ^ hz0) & TMASK];
        g[j*8+2] = tbl[(hx0 ^ hy1 ^ hz0) & TMASK];
        g[j*8+3] = tbl[(hx1 ^ hy1 ^ hz0) & TMASK];
        g[j*8+4] = tbl[(hx0 ^ hy0 ^ hz1) & TMASK];
        g[j*8+5] = tbl[(hx1 ^ hy0 ^ hz1) & TMASK];
        g[j*8+6] = tbl[(hx0 ^ hy1 ^ hz1) & TMASK];
        g[j*8+7] = tbl[(hx1 ^ hy1 ^ hz1) & TMASK];
    }
}

__device__ __forceinline__ void consume_batch(const float2 (&g)[NB * 8],
                                              const Frac (&fr)[NB],
                                              float* __restrict__ o)
{
    float buf[NB * 2];
    #pragma unroll
    for (int j = 0; j < NB; ++j) {
        float tx = fr[j].tx, ty = fr[j].ty, tz = fr[j].tz;
        float wx1 = tx, wx0 = 1.0f - tx;
        float wy1 = ty, wy0 = 1.0f - ty;
        float wz1 = tz, wz0 = 1.0f - tz;
        float wz0y0 = wy0 * wz0, wz0y1 = wy1 * wz0;
        float wz1y0 = wy0 * wz1, wz1y1 = wy1 * wz1;
        float w0 = wx0 * wz0y0, w1 = wx1 * wz0y0;
        float w2 = wx0 * wz0y1, w3 = wx1 * wz0y1;
        float w4 = wx0 * wz1y0, w5 = wx1 * wz1y0;
        float w6 = wx0 * wz1y1, w7 = wx1 * wz1y1;

        buf[2*j+0] = w0*g[j*8+0].x + w1*g[j*8+1].x + w2*g[j*8+2].x + w3*g[j*8+3].x
                   + w4*g[j*8+4].x + w5*g[j*8+5].x + w6*g[j*8+6].x + w7*g[j*8+7].x;
        buf[2*j+1] = w0*g[j*8+0].y + w1*g[j*8+1].y + w2*g[j*8+2].y + w3*g[j*8+3].y
                   + w4*g[j*8+4].y + w5*g[j*8+5].y + w6*g[j*8+6].y + w7*g[j*8+7].y;
    }
    f32x4 v0 = { buf[0], buf[1], buf[2], buf[3] };
    f32x4 v1 = { buf[4], buf[5], buf[6], buf[7] };
    __builtin_nontemporal_store(v0, (f32x4*)(o + 0));
    __builtin_nontemporal_store(v1, (f32x4*)(o + 4));
}

__global__ __launch_bounds__(256, 2)
void hashgrid3d_kernel(const float* __restrict__ xyt,
                       const float* __restrict__ tables,
                       float* __restrict__ out, int n)
{
    int p = blockIdx.x * 256 + threadIdx.x;
    if (p >= n) return;

    float x = xyt[3 * p + 0];
    float y = xyt[3 * p + 1];
    float z = xyt[3 * p + 2];

    const float2* tbl2 = (const float2*)tables;
    float* o = out + (size_t)p * 32;

    float2 gA[NB * 8], gB[NB * 8];
    Frac  frA[NB], frB[NB];

    // depth-2 pipeline over 4 batches of 4 levels
    issue_batch<0>(tbl2, x, y, z, gA, frA);
    issue_batch<4>(tbl2, x, y, z, gB, frB);
    consume_batch(gA, frA, o + 0);          // waits only gA's 32 loads
    issue_batch<8>(tbl2, x, y, z, gA, frA);
    consume_batch(gB, frB, o + 8);
    issue_batch<12>(tbl2, x, y, z, gB, frB);
    consume_batch(gA, frA, o + 16);
    consume_batch(gB, frB, o + 24);
}

extern "C" void kernel_launch(void* const* d_in, const int* in_sizes, int n_in,
                              void* d_out, int out_size, void* d_ws, size_t ws_size,
                              hipStream_t stream) {
    const float* xyt    = (const float*)d_in[0];   // (1048576, 3) f32
    const float* tables = (const float*)d_in[1];   // (16, 524288, 2) f32
    float* out = (float*)d_out;                    // (1048576, 32) f32
    int n = in_sizes[0] / 3;
    int blocks = (n + 255) / 256;
    hashgrid3d_kernel<<<blocks, 256, 0, stream>>>(xyt, tables, out, n);
}

// Round 3
// 812.778 us; speedup vs baseline: 1.0030x; 1.0030x over previous
//
#include <hip/hip_runtime.h>
#include <stdint.h>

// HashGrid3D: L=16 levels, T=2^19 entries/level, F=2 features, trilinear interp.
// One thread per point, latency-bound random gathers. Round-2 lesson: the
// pressure-aware scheduler sank all loads next to their uses (VGPR=32, ~8
// loads in flight). This version pins the software pipeline with
// __builtin_amdgcn_sched_barrier(0) fences so 2 batches x 32 float2 loads
// stay in flight across the consume of the older batch (~64 outstanding
// loads/wave). launch_bounds(256,2) gives the RA a 256-VGPR budget so the
// ~150-VGPR live set does not spill.

constexpr int   LVL   = 16;
constexpr int   TBL   = 524288;          // 2^19
constexpr uint32_t TMASK = 0x7FFFFu;     // T-1
constexpr uint32_t P2 = 2654435761u;
constexpr uint32_t P3 = 805459861u;
// RES[l] = round(16 * (512/16)^(l/15))
constexpr int RESV[LVL] = {16, 20, 25, 32, 40, 51, 64, 81,
                           102, 128, 161, 203, 256, 323, 406, 512};

constexpr int NB = 4;                    // levels per batch

typedef float f32x4 __attribute__((ext_vector_type(4)));

#define SB() __builtin_amdgcn_sched_barrier(0)

struct Frac { float tx, ty, tz; };

template<int L0>
__device__ __forceinline__ void issue_batch(const float2* __restrict__ tables,
                                            float x, float y, float z,
                                            float2 (&g)[NB * 8], Frac (&fr)[NB])
{
    #pragma unroll
    for (int j = 0; j < NB; ++j) {
        const int l = L0 + j;            // compile-time after unroll
        const int N = RESV[l];
        const float2* __restrict__ tbl = tables + (size_t)l * TBL;

        float sx = x * (float)N, sy = y * (float)N, sz = z * (float)N;
        float fx = floorf(sx), fy = floorf(sy), fz = floorf(sz);
        fr[j].tx = sx - fx; fr[j].ty = sy - fy; fr[j].tz = sz - fz;
        int ix = (int)fx, iy = (int)fy, iz = (int)fz;

        // reference applies (i0 + off) % N to every corner; i0 can hit N on
        // the fp rounding edge, so wrap corner 0 too.
        int ix0 = (ix >= N) ? ix - N : ix;
        int iy0 = (iy >= N) ? iy - N : iy;
        int iz0 = (iz >= N) ? iz - N : iz;
        int ix1 = ix + 1; ix1 = (ix1 >= N) ? ix1 - N : ix1;
        int iy1 = iy + 1; iy1 = (iy1 >= N) ? iy1 - N : iy1;
        int iz1 = iz + 1; iz1 = (iz1 >= N) ? iz1 - N : iz1;

        uint32_t hx0 = (uint32_t)ix0;           // prime 1
        uint32_t hx1 = (uint32_t)ix1;
        uint32_t hy0 = (uint32_t)iy0 * P2;
        uint32_t hy1 = (uint32_t)iy1 * P2;
        uint32_t hz0 = (uint32_t)iz0 * P3;
        uint32_t hz1 = (uint32_t)iz1 * P3;

        g[j*8+0] = tbl[(hx0 ^ hy0 ^ hz0) & TMASK];
        g[j*8+1] = tbl[(hx1 ^ hy0 ^ hz0) & TMASK];
        g[j*8+2] = tbl[(hx0 ^ hy1 ^ hz0) & TMASK];
        g[j*8+3] = tbl[(hx1 ^ hy1 ^ hz0) & TMASK];
        g[j*8+4] = tbl[(hx0 ^ hy0 ^ hz1) & TMASK];
        g[j*8+5] = tbl[(hx1 ^ hy0 ^ hz1) & TMASK];
        g[j*8+6] = tbl[(hx0 ^ hy1 ^ hz1) & TMASK];
        g[j*8+7] = tbl[(hx1 ^ hy1 ^ hz1) & TMASK];
    }
}

__device__ __forceinline__ void consume_batch(const float2 (&g)[NB * 8],
                                              const Frac (&fr)[NB],
                                              float* __restrict__ o)
{
    float buf[NB * 2];
    #pragma unroll
    for (int j = 0; j < NB; ++j) {
        float tx = fr[j].tx, ty = fr[j].ty, tz = fr[j].tz;
        float wx1 = tx, wx0 = 1.0f - tx;
        float wy1 = ty, wy0 = 1.0f - ty;
        float wz1 = tz, wz0 = 1.0f - tz;
        float wz0y0 = wy0 * wz0, wz0y1 = wy1 * wz0;
        float wz1y0 = wy0 * wz1, wz1y1 = wy1 * wz1;
        float w0 = wx0 * wz0y0, w1 = wx1 * wz0y0;
        float w2 = wx0 * wz0y1, w3 = wx1 * wz0y1;
        float w4 = wx0 * wz1y0, w5 = wx1 * wz1y0;
        float w6 = wx0 * wz1y1, w7 = wx1 * wz1y1;

        buf[2*j+0] = w0*g[j*8+0].x + w1*g[j*8+1].x + w2*g[j*8+2].x + w3*g[j*8+3].x
                   + w4*g[j*8+4].x + w5*g[j*8+5].x + w6*g[j*8+6].x + w7*g[j*8+7].x;
        buf[2*j+1] = w0*g[j*8+0].y + w1*g[j*8+1].y + w2*g[j*8+2].y + w3*g[j*8+3].y
                   + w4*g[j*8+4].y + w5*g[j*8+5].y + w6*g[j*8+6].y + w7*g[j*8+7].y;
    }
    f32x4 v0 = { buf[0], buf[1], buf[2], buf[3] };
    f32x4 v1 = { buf[4], buf[5], buf[6], buf[7] };
    __builtin_nontemporal_store(v0, (f32x4*)(o + 0));
    __builtin_nontemporal_store(v1, (f32x4*)(o + 4));
}

__global__ __launch_bounds__(256, 2)
void hashgrid3d_kernel(const float* __restrict__ xyt,
                       const float* __restrict__ tables,
                       float* __restrict__ out, int n)
{
    int p = blockIdx.x * 256 + threadIdx.x;
    if (p >= n) return;

    float x = xyt[3 * p + 0];
    float y = xyt[3 * p + 1];
    float z = xyt[3 * p + 2];

    const float2* tbl2 = (const float2*)tables;
    float* o = out + (size_t)p * 32;

    float2 gA[NB * 8], gB[NB * 8];
    Frac  frA[NB], frB[NB];

    // depth-2 pipeline over 4 batches of 4 levels; sched_barrier(0) fences
    // forbid the scheduler from sinking batch b+1's loads below batch b's
    // consume (that is exactly what it did in round 2, collapsing MLP to 8).
    issue_batch<0>(tbl2, x, y, z, gA, frA);
    SB();
    issue_batch<4>(tbl2, x, y, z, gB, frB);
    SB();
    consume_batch(gA, frA, o + 0);          // waits gA only; gB stays in flight
    SB();
    issue_batch<8>(tbl2, x, y, z, gA, frA);
    SB();
    consume_batch(gB, frB, o + 8);
    SB();
    issue_batch<12>(tbl2, x, y, z, gB, frB);
    SB();
    consume_batch(gA, frA, o + 16);
    SB();
    consume_batch(gB, frB, o + 24);
}

extern "C" void kernel_launch(void* const* d_in, const int* in_sizes, int n_in,
                              void* d_out, int out_size, void* d_ws, size_t ws_size,
                              hipStream_t stream) {
    const float* xyt    = (const float*)d_in[0];   // (1048576, 3) f32
    const float* tables = (const float*)d_in[1];   // (16, 524288, 2) f32
    float* out = (float*)d_out;                    // (1048576, 32) f32
    int n = in_sizes[0] / 3;
    int blocks = (n + 255) / 256;
    hashgrid3d_kernel<<<blocks, 256, 0, stream>>>(xyt, tables, out, n);
}